// Round 5
// baseline (468.203 us; speedup 1.0000x reference)
//
#include <hip/hip_runtime.h>
#include <hip/hip_bf16.h>
#include <stdint.h>

#define BATCH 8
#define SEQ 2048
#define DMODEL 1024

typedef __attribute__((ext_vector_type(4))) float f32x4;
typedef __attribute__((ext_vector_type(8))) short bf16x8;
typedef __attribute__((ext_vector_type(4))) uint32_t u32x4;
typedef __attribute__((ext_vector_type(2))) uint32_t u32x2;

#define MFMA16(a, b, c) __builtin_amdgcn_mfma_f32_16x16x32_bf16((a), (b), (c), 0, 0, 0)

static __device__ __forceinline__ uint16_t f2bf(float f) {
    uint32_t u = __builtin_bit_cast(uint32_t, f);
    u += 0x7fffu + ((u >> 16) & 1u);   // round-to-nearest-even
    return (uint16_t)(u >> 16);
}
static __device__ __forceinline__ uint32_t pk2(float lo, float hi) {
    return (uint32_t)f2bf(lo) | ((uint32_t)f2bf(hi) << 16);
}
// async global->LDS, 16B per lane. LDS dest is wave-uniform base + lane*16.
static __device__ __forceinline__ void gload16(const uint16_t* g, uint16_t* l) {
    __builtin_amdgcn_global_load_lds((const __attribute__((address_space(1))) void*)g,
                                     (__attribute__((address_space(3))) void*)l, 16, 0, 0);
}

// ---------------------------------------------------------------------------
// Kernel 0: f32 -> bf16 cast, 8 elems/thread (memory-bound).
// ---------------------------------------------------------------------------
__global__ __launch_bounds__(256) void cast_bf16(const float* __restrict__ src,
                                                 uint16_t* __restrict__ dst) {
    const size_t i = ((size_t)blockIdx.x * 256 + threadIdx.x) * 8;
    f32x4 a = *(const f32x4*)(src + i);
    f32x4 b = *(const f32x4*)(src + i + 4);
    u32x4 o = {pk2(a[0], a[1]), pk2(a[2], a[3]), pk2(b[0], b[1]), pk2(b[2], b[3])};
    *(u32x4*)(dst + i) = o;
}

// ---------------------------------------------------------------------------
// Kernel 1: cast + transpose weights. WT[z][n][k] = W_z[k][n], bf16.
// ---------------------------------------------------------------------------
__global__ void wt_cast_kernel(const float* __restrict__ Wk, const float* __restrict__ Wv,
                               const float* __restrict__ Wq, uint16_t* __restrict__ WT) {
    const float* W = blockIdx.z == 0 ? Wk : (blockIdx.z == 1 ? Wv : Wq);
    uint16_t* dst = WT + (size_t)blockIdx.z * DMODEL * DMODEL;
    __shared__ float tile[32][33];
    const int x = blockIdx.x * 32, y = blockIdx.y * 32;
    const int tx = threadIdx.x, ty = threadIdx.y;
#pragma unroll
    for (int j = 0; j < 4; j++)
        tile[ty * 4 + j][tx] = W[(size_t)(y + ty * 4 + j) * DMODEL + x + tx];
    __syncthreads();
#pragma unroll
    for (int j = 0; j < 4; j++)
        dst[(size_t)(x + ty * 4 + j) * DMODEL + y + tx] = f2bf(tile[tx][ty * 4 + j]);
}

// ---------------------------------------------------------------------------
// Kernel 2: pipelined 256x256 B^T GEMM.  C[b][m][n] = sum_k A[b][m][k]*Bt[b][n][k]
// 8 waves (2Mx4N), BK=32, 3-slot LDS rotation, prefetch depth 2,
// counted vmcnt(8) (never drained in main loop), raw s_barrier, setprio MFMA.
//
// FRAGMENT-MAJOR LDS LAYOUT (bank-conflict fix): tile element (row,k) lives at
// elem offset (row>>4)*512 + (k>>3)*128 + (row&15)*8 + (k&7).  A wave's
// fragment read (block bi, lanes (lr,lg)) is bi*512 + lg*128 + lr*8: lane l
// reads byte l*16 of a contiguous 1KB block -> linear, conflict-free.
// Staging keeps the mandatory linear LDS dest (chunk t -> byte t*16); the
// per-lane GLOBAL source is permuted instead: chunk c sources
// row=(c>>6)*16+(c&15), kslot=(c>>4)&3.  Per-wave footprint per instruction
// is the same 16 full rows as before (lane-permuted only).
//
// BX=1: batch on blockIdx.x -> XCD = batch (per-XCD L2 working set).
// MODE 0: bf16 C[m][n] * scale.  MODE 1: bf16 V-transpose store out[b][n][s].
// MODE 2: f32 C[m][n] * Linv[row].
// ---------------------------------------------------------------------------
#define STAGE(tile, s)                                        \
    do {                                                      \
        const size_t ko_ = (size_t)(tile) * 32;               \
        gload16(Ab + ko_ + aoff0, &As[s][t * 8]);             \
        gload16(Ab + ko_ + aoff1, &As[s][t * 8 + 4096]);      \
        gload16(Bb + ko_ + boff0, &Bs[s][t * 8]);             \
        gload16(Bb + ko_ + boff1, &Bs[s][t * 8 + 4096]);      \
    } while (0)

#define KBODY(s, WAITSTR)                                                              \
    do {                                                                               \
        asm volatile("s_waitcnt " WAITSTR ::: "memory");                               \
        __builtin_amdgcn_s_barrier();                                                  \
        bf16x8 bfr[4], afr[8];                                                         \
        _Pragma("unroll") for (int j = 0; j < 4; j++)                                  \
            bfr[j] = *(const bf16x8*)&Bs[s][(wc * 4 + j) * 512 + lg * 128 + lr * 8];   \
        _Pragma("unroll") for (int i = 0; i < 8; i++)                                  \
            afr[i] = *(const bf16x8*)&As[s][(wr * 8 + i) * 512 + lg * 128 + lr * 8];   \
        __builtin_amdgcn_s_setprio(1);                                                 \
        _Pragma("unroll") for (int i = 0; i < 4; i++)                                  \
            _Pragma("unroll") for (int j = 0; j < 4; j++)                              \
                acc[i][j] = MFMA16(afr[i], bfr[j], acc[i][j]);                         \
        __builtin_amdgcn_s_setprio(0);                                                 \
        __builtin_amdgcn_s_setprio(1);                                                 \
        _Pragma("unroll") for (int i = 4; i < 8; i++)                                  \
            _Pragma("unroll") for (int j = 0; j < 4; j++)                              \
                acc[i][j] = MFMA16(afr[i], bfr[j], acc[i][j]);                         \
        __builtin_amdgcn_s_setprio(0);                                                 \
        asm volatile("s_waitcnt lgkmcnt(0)" ::: "memory");                             \
        __builtin_amdgcn_sched_barrier(0);                                             \
        __builtin_amdgcn_s_barrier();                                                  \
    } while (0)

template <int MODE, int BX>
__global__ __launch_bounds__(512, 2) void gemm256(const uint16_t* __restrict__ Ag,
                                                  const uint16_t* __restrict__ Bg,
                                                  void* __restrict__ Cg,
                                                  const float* __restrict__ Linv,
                                                  float scale, int lda, int ldb, int ldc,
                                                  int nk, size_t sA, size_t sB, size_t sC) {
    __shared__ __align__(16) uint16_t As[3][256 * 32];
    __shared__ __align__(16) uint16_t Bs[3][256 * 32];
    const int bz = BX ? blockIdx.x : blockIdx.z;
    const int bm = BX ? blockIdx.y : blockIdx.x;
    const int bn = BX ? blockIdx.z : blockIdx.y;
    const int m0 = bm * 256, n0 = bn * 256;
    const uint16_t* Ab = Ag + (size_t)bz * sA + (size_t)m0 * lda;
    const uint16_t* Bb = Bg + (size_t)bz * sB + (size_t)n0 * ldb;
    const int t = threadIdx.x, lane = t & 63;
    const int wid = t >> 6, wr = wid >> 2, wc = wid & 3;
    const int lr = lane & 15, lg = lane >> 4;
    // staging source permutation: chunk c (= t, t+512) -> row, k-slot
    const int srow = ((t >> 6) << 4) | (t & 15);   // (block)*16 + row-in-block
    const int sks = (t >> 4) & 3;                  // 8-elem k-slot
    const size_t aoff0 = (size_t)srow * lda + sks * 8;
    const size_t aoff1 = aoff0 + (size_t)128 * lda;   // chunks t+512: rows +128
    const size_t boff0 = (size_t)srow * ldb + sks * 8;
    const size_t boff1 = boff0 + (size_t)128 * ldb;

    f32x4 acc[8][4] = {};
    STAGE(0, 0);
    STAGE(1, 1);
    int s = 0, s2 = 2;
    for (int kt = 0; kt < nk - 2; ++kt) {
        STAGE(kt + 2, s2);
        KBODY(s, "vmcnt(8)");
        s = (s == 2) ? 0 : s + 1;
        s2 = (s2 == 2) ? 0 : s2 + 1;
    }
    KBODY(s, "vmcnt(4)");
    s = (s == 2) ? 0 : s + 1;
    KBODY(s, "vmcnt(0)");

    if constexpr (MODE == 0) {
        uint16_t* C = (uint16_t*)Cg + (size_t)bz * sC;
#pragma unroll
        for (int i = 0; i < 8; i++) {
            const int gm = m0 + wr * 128 + i * 16 + lg * 4;
#pragma unroll
            for (int j = 0; j < 4; j++) {
                const int gn = n0 + wc * 64 + j * 16 + lr;
#pragma unroll
                for (int r = 0; r < 4; r++)
                    C[(size_t)(gm + r) * ldc + gn] = f2bf(acc[i][j][r] * scale);
            }
        }
    } else if constexpr (MODE == 1) {
        uint16_t* C = (uint16_t*)Cg;
#pragma unroll
        for (int i = 0; i < 8; i++) {
            const int gm = m0 + wr * 128 + i * 16 + lg * 4;  // global m = b*SEQ + s
            const int bb = gm / SEQ;                         // 256 | SEQ: uniform per block
            const int sx = gm - bb * SEQ;
#pragma unroll
            for (int j = 0; j < 4; j++) {
                const int e = n0 + wc * 64 + j * 16 + lr;
                u32x2 v = {pk2(acc[i][j][0], acc[i][j][1]), pk2(acc[i][j][2], acc[i][j][3])};
                *(u32x2*)&C[((size_t)bb * DMODEL + e) * SEQ + sx] = v;
            }
        }
    } else {
        float* C = (float*)Cg + (size_t)bz * sC;
        const float* LB = Linv + bz * SEQ;
#pragma unroll
        for (int i = 0; i < 8; i++) {
            const int gm = m0 + wr * 128 + i * 16 + lg * 4;
            const f32x4 lv = *(const f32x4*)&LB[gm];
#pragma unroll
            for (int j = 0; j < 4; j++) {
                const int gn = n0 + wc * 64 + j * 16 + lr;
#pragma unroll
                for (int r = 0; r < 4; r++)
                    C[(size_t)(gm + r) * ldc + gn] = acc[i][j][r] * lv[r];
            }
        }
    }
}

// ---------------------------------------------------------------------------
// Kernel 3: row softmax, in place.  One block per row (16384 blocks).
// ---------------------------------------------------------------------------
__global__ __launch_bounds__(256) void softmax_rows(uint16_t* __restrict__ S,
                                                    float* __restrict__ Linv) {
    const size_t row = blockIdx.x;
    uint16_t* s = S + row * SEQ;
    const int t = threadIdx.x, lane = t & 63, w = t >> 6;
    __shared__ float redm[4], reds[4];
    u32x4 raw = *(const u32x4*)(s + t * 8);
    float v[8];
#pragma unroll
    for (int j = 0; j < 4; j++) {
        v[2 * j]     = __builtin_bit_cast(float, raw[j] << 16);
        v[2 * j + 1] = __builtin_bit_cast(float, raw[j] & 0xffff0000u);
    }
    float m = v[0];
#pragma unroll
    for (int i = 1; i < 8; i++) m = fmaxf(m, v[i]);
#pragma unroll
    for (int d = 1; d < 64; d <<= 1) m = fmaxf(m, __shfl_xor(m, d));
    if (lane == 0) redm[w] = m;
    __syncthreads();
    m = fmaxf(fmaxf(redm[0], redm[1]), fmaxf(redm[2], redm[3]));
    float p[8], sum = 0.0f;
#pragma unroll
    for (int i = 0; i < 8; i++) { p[i] = __expf(v[i] - m); sum += p[i]; }
#pragma unroll
    for (int d = 1; d < 64; d <<= 1) sum += __shfl_xor(sum, d);
    if (lane == 0) reds[w] = sum;
    __syncthreads();
    sum = reds[0] + reds[1] + reds[2] + reds[3];
    u32x4 outp;
#pragma unroll
    for (int j = 0; j < 4; j++) outp[j] = pk2(p[2 * j], p[2 * j + 1]);
    *(u32x4*)(s + t * 8) = outp;
    if (t == 0) Linv[row] = 1.0f / sum;
}

// ---------------------------------------------------------------------------
// Workspace layout (bytes):
//   Qbf [16384][1024] bf16 :          0   (Q pre-scaled by 1/32)
//   Kbf [16384][1024] bf16 :  33,554,432
//   VTb [8][1024][2048] bf16: 67,108,864
//   WT  [3][1024][1024] bf16:100,663,296
//   Linv[16384] f32        : 106,954,752
//   S/P [8][2048][2048] bf16:107,020,288  (P in place)
//   Xbf [16384][1024] bf16 :171,966,464   (reused for Xq, Xk, Xv in turn)
// ---------------------------------------------------------------------------
extern "C" void kernel_launch(void* const* d_in, const int* in_sizes, int n_in,
                              void* d_out, int out_size, void* d_ws, size_t ws_size,
                              hipStream_t stream) {
    const float* Xk = (const float*)d_in[0];
    const float* Xv = (const float*)d_in[1];
    const float* Xq = (const float*)d_in[2];
    const float* Wk = (const float*)d_in[3];
    const float* Wv = (const float*)d_in[4];
    const float* Wq = (const float*)d_in[5];
    float* out = (float*)d_out;
    char* ws = (char*)d_ws;
    uint16_t* Qbf = (uint16_t*)(ws);
    uint16_t* Kbf = (uint16_t*)(ws + (size_t)33554432);
    uint16_t* VTb = (uint16_t*)(ws + (size_t)67108864);
    uint16_t* WT  = (uint16_t*)(ws + (size_t)100663296);
    float*    Linv= (float*)(ws + (size_t)106954752);
    uint16_t* Sb  = (uint16_t*)(ws + (size_t)107020288);
    uint16_t* Xbf = (uint16_t*)(ws + (size_t)171966464);

    wt_cast_kernel<<<dim3(32, 32, 3), dim3(32, 8), 0, stream>>>(Wk, Wv, Wq, WT);
    // Q projection (scale 1/sqrt(1024) folded into bf16 store). Weights (2 MB)
    // are L2-resident per XCD -> keep m-tile on x here.
    cast_bf16<<<8192, 256, 0, stream>>>(Xq, Xbf);
    gemm256<0, 0><<<dim3(64, 4, 1), 512, 0, stream>>>(
        Xbf, WT + 2 * 1048576, (void*)Qbf, nullptr, 0.03125f,
        DMODEL, DMODEL, DMODEL, DMODEL / 32, 0, 0, 0);
    // K projection
    cast_bf16<<<8192, 256, 0, stream>>>(Xk, Xbf);
    gemm256<0, 0><<<dim3(64, 4, 1), 512, 0, stream>>>(
        Xbf, WT, (void*)Kbf, nullptr, 1.0f,
        DMODEL, DMODEL, DMODEL, DMODEL / 32, 0, 0, 0);
    // V projection with transposed store -> VT[b][e][s]
    cast_bf16<<<8192, 256, 0, stream>>>(Xv, Xbf);
    gemm256<1, 0><<<dim3(64, 4, 1), 512, 0, stream>>>(
        Xbf, WT + 1048576, (void*)VTb, nullptr, 1.0f,
        DMODEL, DMODEL, 0, DMODEL / 32, 0, 0, 0);
    // scores: S[b][q][k] = Qhat[b] . K[b]^T   (bf16 store)
    // batch on blockIdx.x -> XCD = batch: per-XCD working set = Q_b + K_b (8.4 MB)
    gemm256<0, 1><<<dim3(8, 8, 8), 512, 0, stream>>>(
        Qbf, Kbf, (void*)Sb, nullptr, 1.0f,
        DMODEL, DMODEL, SEQ, DMODEL / 32,
        (size_t)SEQ * DMODEL, (size_t)SEQ * DMODEL, (size_t)SEQ * SEQ);
    // in-place row softmax -> P, Linv
    softmax_rows<<<dim3(BATCH * SEQ), 256, 0, stream>>>(Sb, Linv);
    // Z[b][q][e] = (P[b] . V[b]) * Linv  (f32 store), batch on x again
    gemm256<2, 1><<<dim3(8, 8, 4), 512, 0, stream>>>(
        Sb, VTb, (void*)out, Linv, 1.0f,
        SEQ, SEQ, DMODEL, SEQ / 32,
        (size_t)SEQ * SEQ, (size_t)DMODEL * SEQ, (size_t)SEQ * DMODEL);
}

// Round 6
// 405.703 us; speedup vs baseline: 1.1541x; 1.1541x over previous
//
#include <hip/hip_runtime.h>
#include <hip/hip_bf16.h>
#include <stdint.h>

#define BATCH 8
#define SEQ 2048
#define DMODEL 1024

typedef __attribute__((ext_vector_type(4))) float f32x4;
typedef __attribute__((ext_vector_type(8))) short bf16x8;
typedef __attribute__((ext_vector_type(4))) uint32_t u32x4;
typedef __attribute__((ext_vector_type(2))) uint32_t u32x2;

#define MFMA16(a, b, c) __builtin_amdgcn_mfma_f32_16x16x32_bf16((a), (b), (c), 0, 0, 0)

// ---------------------------------------------------------------------------
// PK ("panel-k-major") operand layout, used for ALL bf16 GEMM operands:
//   elem(r,k) at offset (r>>4)*(Kd*16) + (k>>3)*128 + (r&15)*8 + (k&7)
// Properties:
//  * a BK=32 K-tile of 256 rows = 16 blocks x contiguous 512 elems -> staging
//    is 1KB-contiguous per wave instruction (perfect coalescing), lane-linear
//    LDS dest (global_load_lds-legal);
//  * LDS tile image = [block][kslot][row15][8]: fragment read for MFMA
//    16x16x32 is lane-linear (lane l reads byte l*16) -> zero bank conflicts.
// ---------------------------------------------------------------------------

static __device__ __forceinline__ uint16_t f2bf(float f) {
    uint32_t u = __builtin_bit_cast(uint32_t, f);
    u += 0x7fffu + ((u >> 16) & 1u);   // round-to-nearest-even
    return (uint16_t)(u >> 16);
}
static __device__ __forceinline__ uint32_t pk2(float lo, float hi) {
    return (uint32_t)f2bf(lo) | ((uint32_t)f2bf(hi) << 16);
}
// async global->LDS, 16B per lane. LDS dest is wave-uniform base + lane*16.
static __device__ __forceinline__ void gload16(const uint16_t* g, uint16_t* l) {
    __builtin_amdgcn_global_load_lds((const __attribute__((address_space(1))) void*)g,
                                     (__attribute__((address_space(3))) void*)l, 16, 0, 0);
}

// ---------------------------------------------------------------------------
// Kernel 0: f32 row-major -> bf16 PK cast. Thread handles one PK chunk
// (8 contiguous k of one row). Stores fully coalesced; source is 32B granules
// at 4KB stride (bounded 2x read-amp, latency-hidden).
// ---------------------------------------------------------------------------
__global__ __launch_bounds__(256) void cast_bf16_pk(const float* __restrict__ src,
                                                    uint16_t* __restrict__ dst) {
    const size_t c = (size_t)blockIdx.x * 256 + threadIdx.x;  // PK chunk id
    const size_t panel = c >> 11;           // 2048 chunks per 16x1024 panel
    const int w = (int)(c & 2047);
    const int ks = w >> 4, r15 = w & 15;
    const float* s = src + (panel * 16 + r15) * DMODEL + ks * 8;
    f32x4 a = *(const f32x4*)s;
    f32x4 b = *(const f32x4*)(s + 4);
    u32x4 o = {pk2(a[0], a[1]), pk2(a[2], a[3]), pk2(b[0], b[1]), pk2(b[2], b[3])};
    *(u32x4*)(dst + c * 8) = o;
}

// ---------------------------------------------------------------------------
// Kernel 1: cast + transpose weights into PK.  WT_pk(n,k) = W[k][n].
// ---------------------------------------------------------------------------
__global__ void wt_cast_kernel(const float* __restrict__ Wk, const float* __restrict__ Wv,
                               const float* __restrict__ Wq, uint16_t* __restrict__ WT) {
    const float* W = blockIdx.z == 0 ? Wk : (blockIdx.z == 1 ? Wv : Wq);
    uint16_t* dst = WT + (size_t)blockIdx.z * DMODEL * DMODEL;
    __shared__ float tile[32][33];
    const int x = blockIdx.x * 32, y = blockIdx.y * 32;
    const int tx = threadIdx.x, ty = threadIdx.y;
#pragma unroll
    for (int j = 0; j < 4; j++)
        tile[ty * 4 + j][tx] = W[(size_t)(y + ty * 4 + j) * DMODEL + x + tx];
    __syncthreads();
#pragma unroll
    for (int j = 0; j < 4; j++) {
        const int n = x + ty * 4 + j, k = y + tx;
        const size_t off = ((size_t)(n >> 4) * (DMODEL / 8) + (k >> 3)) * 128 +
                           (n & 15) * 8 + (k & 7);
        dst[off] = f2bf(tile[tx][ty * 4 + j]);
    }
}

// ---------------------------------------------------------------------------
// Kernel 2: pipelined 256x256 B^T GEMM on PK operands.
//   C[b][m][n] = sum_k A[b][m][k] * Bt[b][n][k]
// 8 waves (2Mx4N), BK=32, 3-slot LDS rotation, prefetch depth 2,
// counted vmcnt(8), raw s_barrier, setprio MFMA.  Staging is 1KB-contiguous
// per wave instruction; fragment ds_reads are lane-linear (0 conflicts).
// BX=1: batch on blockIdx.x -> XCD = batch.
// MODE 0: bf16 C in PK (Kd=ldc), * scale.   MODE 1: bf16 V-transpose into
// PK over [e][s] (Kd=SEQ).                  MODE 2: f32 plain C * Linv[row].
// ---------------------------------------------------------------------------
#define STAGE(tile, s)                                        \
    do {                                                      \
        const size_t ko_ = (size_t)(tile) * 512;              \
        gload16(Ab + ko_ + abase0, &As[s][t * 8]);            \
        gload16(Ab + ko_ + abase1, &As[s][t * 8 + 4096]);     \
        gload16(Bb + ko_ + bbase0, &Bs[s][t * 8]);            \
        gload16(Bb + ko_ + bbase1, &Bs[s][t * 8 + 4096]);     \
    } while (0)

#define KBODY(s, WAITSTR)                                                              \
    do {                                                                               \
        asm volatile("s_waitcnt " WAITSTR ::: "memory");                               \
        __builtin_amdgcn_s_barrier();                                                  \
        bf16x8 bfr[4], afr[8];                                                         \
        _Pragma("unroll") for (int j = 0; j < 4; j++)                                  \
            bfr[j] = *(const bf16x8*)&Bs[s][(wc * 4 + j) * 512 + lg * 128 + lr * 8];   \
        _Pragma("unroll") for (int i = 0; i < 8; i++)                                  \
            afr[i] = *(const bf16x8*)&As[s][(wr * 8 + i) * 512 + lg * 128 + lr * 8];   \
        __builtin_amdgcn_s_setprio(1);                                                 \
        _Pragma("unroll") for (int i = 0; i < 4; i++)                                  \
            _Pragma("unroll") for (int j = 0; j < 4; j++)                              \
                acc[i][j] = MFMA16(afr[i], bfr[j], acc[i][j]);                         \
        __builtin_amdgcn_s_setprio(0);                                                 \
        __builtin_amdgcn_s_setprio(1);                                                 \
        _Pragma("unroll") for (int i = 4; i < 8; i++)                                  \
            _Pragma("unroll") for (int j = 0; j < 4; j++)                              \
                acc[i][j] = MFMA16(afr[i], bfr[j], acc[i][j]);                         \
        __builtin_amdgcn_s_setprio(0);                                                 \
        asm volatile("s_waitcnt lgkmcnt(0)" ::: "memory");                             \
        __builtin_amdgcn_sched_barrier(0);                                             \
        __builtin_amdgcn_s_barrier();                                                  \
    } while (0)

template <int MODE, int BX>
__global__ __launch_bounds__(512, 2) void gemm256(const uint16_t* __restrict__ Ag,
                                                  const uint16_t* __restrict__ Bg,
                                                  void* __restrict__ Cg,
                                                  const float* __restrict__ Linv,
                                                  float scale, int lda, int ldb, int ldc,
                                                  int nk, size_t sA, size_t sB, size_t sC) {
    __shared__ __align__(16) uint16_t As[3][256 * 32];
    __shared__ __align__(16) uint16_t Bs[3][256 * 32];
    const int bz = BX ? blockIdx.x : blockIdx.z;
    const int bm = BX ? blockIdx.y : blockIdx.x;
    const int bn = BX ? blockIdx.z : blockIdx.y;
    const int m0 = bm * 256, n0 = bn * 256;
    const uint16_t* Ab = Ag + (size_t)bz * sA + (size_t)m0 * lda;  // = (m0/16)*eldA
    const uint16_t* Bb = Bg + (size_t)bz * sB + (size_t)n0 * ldb;
    const int t = threadIdx.x, lane = t & 63;
    const int wid = t >> 6, wr = wid >> 2, wc = wid & 3;
    const int lr = lane & 15, lg = lane >> 4;
    // PK staging: chunk c in {t, t+512}: 16-row block c>>6, within-block c&63.
    const size_t eldA = (size_t)lda * 16, eldB = (size_t)ldb * 16;
    const size_t abase0 = (size_t)(t >> 6) * eldA + (t & 63) * 8;
    const size_t abase1 = abase0 + 8 * eldA;
    const size_t bbase0 = (size_t)(t >> 6) * eldB + (t & 63) * 8;
    const size_t bbase1 = bbase0 + 8 * eldB;

    f32x4 acc[8][4] = {};
    STAGE(0, 0);
    STAGE(1, 1);
    int s = 0, s2 = 2;
    for (int kt = 0; kt < nk - 2; ++kt) {
        STAGE(kt + 2, s2);
        KBODY(s, "vmcnt(8)");
        s = (s == 2) ? 0 : s + 1;
        s2 = (s2 == 2) ? 0 : s2 + 1;
    }
    KBODY(s, "vmcnt(4)");
    s = (s == 2) ? 0 : s + 1;
    KBODY(s, "vmcnt(0)");

    if constexpr (MODE == 0) {
        uint16_t* C = (uint16_t*)Cg + (size_t)bz * sC;
#pragma unroll
        for (int i = 0; i < 8; i++) {
            const int gm = m0 + wr * 128 + i * 16 + lg * 4;   // gm&15 == lg*4
            const size_t pbase = (size_t)(gm >> 4) * (ldc / 8);
#pragma unroll
            for (int j = 0; j < 4; j++) {
                const int gn = n0 + wc * 64 + j * 16 + lr;
                const size_t off = (pbase + (gn >> 3)) * 128 + (gn & 7);
#pragma unroll
                for (int r = 0; r < 4; r++)
                    C[off + (lg * 4 + r) * 8] = f2bf(acc[i][j][r] * scale);
            }
        }
    } else if constexpr (MODE == 1) {
        uint16_t* C = (uint16_t*)Cg;
#pragma unroll
        for (int i = 0; i < 8; i++) {
            const int gm = m0 + wr * 128 + i * 16 + lg * 4;  // global m = b*SEQ + s
            const int bb = gm / SEQ;                         // uniform per block
            const int s0 = gm - bb * SEQ;                    // s0&7 in {0,4}
            uint16_t* Cb = C + (size_t)bb * DMODEL * SEQ;
#pragma unroll
            for (int j = 0; j < 4; j++) {
                const int e = n0 + wc * 64 + j * 16 + lr;
                const size_t off = ((size_t)(e >> 4) * (SEQ / 8) + (s0 >> 3)) * 128 +
                                   (e & 15) * 8 + (s0 & 7);
                u32x2 v = {pk2(acc[i][j][0], acc[i][j][1]), pk2(acc[i][j][2], acc[i][j][3])};
                *(u32x2*)&Cb[off] = v;
            }
        }
    } else {
        float* C = (float*)Cg + (size_t)bz * sC;
        const float* LB = Linv + bz * SEQ;
#pragma unroll
        for (int i = 0; i < 8; i++) {
            const int gm = m0 + wr * 128 + i * 16 + lg * 4;
            const f32x4 lv = *(const f32x4*)&LB[gm];
#pragma unroll
            for (int j = 0; j < 4; j++) {
                const int gn = n0 + wc * 64 + j * 16 + lr;
#pragma unroll
                for (int r = 0; r < 4; r++)
                    C[(size_t)(gm + r) * ldc + gn] = acc[i][j][r] * lv[r];
            }
        }
    }
}

// ---------------------------------------------------------------------------
// Kernel 3: row softmax on PK-layout S, in place.  One block per 16-row panel
// (contiguous 32KB).  Thread t owns row t&15, k-slots (t>>4)+16u, u=0..15.
// Row reduction: shfl_xor 16/32 within wave + LDS across the 4 waves.
// ---------------------------------------------------------------------------
__global__ __launch_bounds__(256) void softmax_pk(uint16_t* __restrict__ S,
                                                  float* __restrict__ Linv) {
    const size_t panel = blockIdx.x;
    uint16_t* sp = S + panel * (size_t)(16 * SEQ);
    const int t = threadIdx.x, lane = t & 63, w = t >> 6;
    const int r15 = t & 15, ksl = t >> 4;
    __shared__ float rm[4][16], rs[4][16];
    u32x4 raw[16];
    float mx = -3.0e38f;
#pragma unroll
    for (int u = 0; u < 16; u++) {
        raw[u] = *(const u32x4*)&sp[(ksl + u * 16) * 128 + r15 * 8];
#pragma unroll
        for (int j = 0; j < 4; j++) {
            mx = fmaxf(mx, __builtin_bit_cast(float, raw[u][j] << 16));
            mx = fmaxf(mx, __builtin_bit_cast(float, raw[u][j] & 0xffff0000u));
        }
    }
    mx = fmaxf(mx, __shfl_xor(mx, 16));
    mx = fmaxf(mx, __shfl_xor(mx, 32));
    if (lane < 16) rm[w][lane] = mx;
    __syncthreads();
    const float m = fmaxf(fmaxf(rm[0][r15], rm[1][r15]), fmaxf(rm[2][r15], rm[3][r15]));
    float sum = 0.0f;
#pragma unroll
    for (int u = 0; u < 16; u++) {
#pragma unroll
        for (int j = 0; j < 4; j++) {
            float lo = __expf(__builtin_bit_cast(float, raw[u][j] << 16) - m);
            float hi = __expf(__builtin_bit_cast(float, raw[u][j] & 0xffff0000u) - m);
            sum += lo + hi;
            raw[u][j] = pk2(lo, hi);
        }
    }
    sum += __shfl_xor(sum, 16);
    sum += __shfl_xor(sum, 32);
    if (lane < 16) rs[w][lane] = sum;
    __syncthreads();
    const float tot = rs[0][r15] + rs[1][r15] + rs[2][r15] + rs[3][r15];
#pragma unroll
    for (int u = 0; u < 16; u++)
        *(u32x4*)&sp[(ksl + u * 16) * 128 + r15 * 8] = raw[u];
    if (w == 0 && lane < 16) Linv[panel * 16 + lane] = 1.0f / tot;
}

// ---------------------------------------------------------------------------
// Workspace layout (bytes), all bf16 matrices in PK layout:
//   Qbf [16384][1024] :          0   (Q pre-scaled by 1/32)
//   Kbf [16384][1024] :  33,554,432
//   VTb [8][1024][2048]: 67,108,864
//   WT  [3][1024][1024]:100,663,296
//   Linv[16384] f32   : 106,954,752
//   S/P [8][2048][2048]:107,020,288  (P in place)
//   Xbf [16384][1024] :171,966,464  (reused for Xq, Xk, Xv in turn)
// ---------------------------------------------------------------------------
extern "C" void kernel_launch(void* const* d_in, const int* in_sizes, int n_in,
                              void* d_out, int out_size, void* d_ws, size_t ws_size,
                              hipStream_t stream) {
    const float* Xk = (const float*)d_in[0];
    const float* Xv = (const float*)d_in[1];
    const float* Xq = (const float*)d_in[2];
    const float* Wk = (const float*)d_in[3];
    const float* Wv = (const float*)d_in[4];
    const float* Wq = (const float*)d_in[5];
    float* out = (float*)d_out;
    char* ws = (char*)d_ws;
    uint16_t* Qbf = (uint16_t*)(ws);
    uint16_t* Kbf = (uint16_t*)(ws + (size_t)33554432);
    uint16_t* VTb = (uint16_t*)(ws + (size_t)67108864);
    uint16_t* WT  = (uint16_t*)(ws + (size_t)100663296);
    float*    Linv= (float*)(ws + (size_t)106954752);
    uint16_t* Sb  = (uint16_t*)(ws + (size_t)107020288);
    uint16_t* Xbf = (uint16_t*)(ws + (size_t)171966464);

    wt_cast_kernel<<<dim3(32, 32, 3), dim3(32, 8), 0, stream>>>(Wk, Wv, Wq, WT);
    // Q projection (scale 1/sqrt(1024) folded into bf16 store)
    cast_bf16_pk<<<8192, 256, 0, stream>>>(Xq, Xbf);
    gemm256<0, 0><<<dim3(64, 4, 1), 512, 0, stream>>>(
        Xbf, WT + 2 * 1048576, (void*)Qbf, nullptr, 0.03125f,
        DMODEL, DMODEL, DMODEL, DMODEL / 32, 0, 0, 0);
    // K projection
    cast_bf16_pk<<<8192, 256, 0, stream>>>(Xk, Xbf);
    gemm256<0, 0><<<dim3(64, 4, 1), 512, 0, stream>>>(
        Xbf, WT, (void*)Kbf, nullptr, 1.0f,
        DMODEL, DMODEL, DMODEL, DMODEL / 32, 0, 0, 0);
    // V projection with transposed store -> VT PK over [e][s]
    cast_bf16_pk<<<8192, 256, 0, stream>>>(Xv, Xbf);
    gemm256<1, 0><<<dim3(64, 4, 1), 512, 0, stream>>>(
        Xbf, WT + 1048576, (void*)VTb, nullptr, 1.0f,
        DMODEL, DMODEL, 0, DMODEL / 32, 0, 0, 0);
    // scores: S[b][q][k] = Qhat[b] . K[b]^T   (bf16 PK store)
    gemm256<0, 1><<<dim3(8, 8, 8), 512, 0, stream>>>(
        Qbf, Kbf, (void*)Sb, nullptr, 1.0f,
        DMODEL, DMODEL, SEQ, DMODEL / 32,
        (size_t)SEQ * DMODEL, (size_t)SEQ * DMODEL, (size_t)SEQ * SEQ);
    // in-place row softmax -> P, Linv
    softmax_pk<<<dim3(BATCH * SEQ / 16), 256, 0, stream>>>(Sb, Linv);
    // Z[b][q][e] = (P[b] . V[b]) * Linv  (f32 plain store)
    gemm256<2, 1><<<dim3(8, 8, 4), 512, 0, stream>>>(
        Sb, VTb, (void*)out, Linv, 1.0f,
        SEQ, SEQ, DMODEL, SEQ / 32,
        (size_t)SEQ * SEQ, (size_t)DMODEL * SEQ, (size_t)SEQ * DMODEL);
}